// Round 2
// baseline (1629.222 us; speedup 1.0000x reference)
//
#include <hip/hip_runtime.h>
#include <float.h>
#include <stdint.h>

typedef __attribute__((ext_vector_type(8))) short bf16x8;
typedef __attribute__((ext_vector_type(4))) float f32x4;

#define NCH 320      // A*K = 5*64 output channels of GEMM1
#define NCG 20       // 320 / 16 channel-groups
#define CHUNK 64     // rows of x staged per iteration

static __device__ __forceinline__ unsigned short f2bf(float f) {
    union { float f; unsigned int u; } v; v.f = f;
    unsigned int u = v.u;
    u += 0x7FFFu + ((u >> 16) & 1u);   // round-to-nearest-even
    return (unsigned short)(u >> 16);
}

// ---- K0a: seg_start[b] = lower_bound(batch, b), b in [0, B] -----------------
// batch is int32 on the device (harness converts all integer inputs to int32).
__global__ void seg_start_kernel(const int* __restrict__ batch,
                                 int* __restrict__ seg, int n, int b_gr) {
    int b = blockIdx.x * blockDim.x + threadIdx.x;
    if (b > b_gr) return;
    int lo = 0, hi = n;
    while (lo < hi) {
        int mid = (lo + hi) >> 1;
        if (batch[mid] < b) lo = mid + 1; else hi = mid;
    }
    seg[b] = lo;
}

// ---- K0b: pack W1 (f32 [256][320]) into bf16 B-fragment layout --------------
// frag (cg, ks): lane l, elem j  <-  W1[k = ks*32 + (l>>4)*8 + j][c = cg*16 + (l&15)]
__global__ void pack_w1_kernel(const float* __restrict__ W1,
                               unsigned short* __restrict__ w1p) {
    int idx = blockIdx.x * blockDim.x + threadIdx.x;  // (cg*8 + ks)*64 + lane
    if (idx >= NCG * 8 * 64) return;
    int lane = idx & 63;
    int ks = (idx >> 6) & 7;
    int cg = idx >> 9;
    int col = cg * 16 + (lane & 15);
    int kbase = ks * 32 + (lane >> 4) * 8;
    unsigned short* dst = w1p + (size_t)idx * 8;
#pragma unroll
    for (int j = 0; j < 8; ++j)
        dst[j] = f2bf(W1[(size_t)(kbase + j) * NCH + col]);
}

// ---- K1: per-graph fused GEMM1 (bf16 MFMA) + segment reductions -------------
// block = 512 thr (8 waves), one graph per block.
// wave w owns cgs {w, w+8, (w+16 if w<4)}.
// z layout per graph: [0:64)=sum [64:128)=min [128:192)=max [192:256)=mean-sum
//                     [256:320)=std-sum [320:384)=std-sumsq
__global__ __launch_bounds__(512, 4) void aggr_kernel(
    const float* __restrict__ x, const int* __restrict__ seg,
    const unsigned short* __restrict__ w1p, float* __restrict__ z) {
    __shared__ unsigned short xs[CHUNK * 256];  // 32 KB, XOR-swizzled bf16
    const int g = blockIdx.x;
    const int s = seg[g], e = seg[g + 1];
    const int tid = threadIdx.x;
    const int lane = tid & 63;
    const int w = tid >> 6;

    float st0[3], st1[3];
#pragma unroll
    for (int i = 0; i < 3; ++i) {
        int cg = w + 8 * i;
        st0[i] = 0.f; st1[i] = 0.f;
        if (cg >= 4 && cg < 8) st0[i] = FLT_MAX;        // min identity
        else if (cg >= 8 && cg < 12) st0[i] = -FLT_MAX; // max identity
    }

    const bf16x8* wp = (const bf16x8*)w1p;

    for (int c0 = s; c0 < e; c0 += CHUNK) {
        const int rem = min(e - c0, CHUNK);
        __syncthreads();  // previous chunk's LDS reads done
        // ---- stage chunk: f32 -> bf16, zero-pad to 64 rows, XOR swizzle ----
        {
            const float4* xv = (const float4*)x + (size_t)c0 * 64;
#pragma unroll
            for (int i = 0; i < 8; ++i) {
                int idx = tid + i * 512;      // wave-uniform row, lane = c4
                int row = idx >> 6;
                int c4 = idx & 63;
                float4 v = make_float4(0.f, 0.f, 0.f, 0.f);
                if (row < rem) v = xv[row * 64 + c4];
                ushort4 h;
                h.x = f2bf(v.x); h.y = f2bf(v.y);
                h.z = f2bf(v.z); h.w = f2bf(v.w);
                int byt = (row * 512 + c4 * 8) ^ ((row & 7) << 4);
                *(ushort4*)((char*)xs + byt) = h;
            }
        }
        __syncthreads();
        // ---- compute: per owned cg, B-frags hoisted; 4 row-tiles x 8 K-steps
#pragma unroll
        for (int i = 0; i < 3; ++i) {
            if (i == 2 && w >= 4) continue;   // waves 4-7 own only 2 cgs
            const int cg = w + 8 * i;
            bf16x8 bfrag[8];
#pragma unroll
            for (int ks = 0; ks < 8; ++ks)
                bfrag[ks] = wp[(cg * 8 + ks) * 64 + lane];
#pragma unroll
            for (int t = 0; t < 4; ++t) {
                const int row = t * 16 + (lane & 15);       // A row (M)
                const int abase = row * 512 + ((lane >> 4) * 16);
                const int swz = (row & 7) << 4;
                bf16x8 afrag[8];
#pragma unroll
                for (int ks = 0; ks < 8; ++ks)
                    afrag[ks] = *(const bf16x8*)((const char*)xs +
                                                 ((abase + ks * 64) ^ swz));
                f32x4 acc = {0.f, 0.f, 0.f, 0.f};
#pragma unroll
                for (int ks = 0; ks < 8; ++ks)
                    acc = __builtin_amdgcn_mfma_f32_16x16x32_bf16(
                        afrag[ks], bfrag[ks], acc, 0, 0, 0);
                // D layout: row=(lane>>4)*4+r, col=lane&15
                const int rbase = t * 16 + ((lane >> 4) << 2);
                if (cg < 4 || (cg >= 12 && cg < 16)) {       // sum / mean-sum
                    st0[i] += acc[0] + acc[1] + acc[2] + acc[3];
                } else if (cg < 8) {                          // min (mask pads)
#pragma unroll
                    for (int r = 0; r < 4; ++r)
                        if (rbase + r < rem) st0[i] = fminf(st0[i], acc[r]);
                } else if (cg < 12) {                         // max (mask pads)
#pragma unroll
                    for (int r = 0; r < 4; ++r)
                        if (rbase + r < rem) st0[i] = fmaxf(st0[i], acc[r]);
                } else {                                      // std: sum+sumsq
                    st0[i] += acc[0] + acc[1] + acc[2] + acc[3];
                    st1[i] += acc[0] * acc[0] + acc[1] * acc[1] +
                              acc[2] * acc[2] + acc[3] * acc[3];
                }
            }
        }
    }

    // ---- cross-lane reduce over rows (lanes l, l^16, l^32, l^48) & write ---
#pragma unroll
    for (int i = 0; i < 3; ++i) {
        if (i == 2 && w >= 4) continue;
        const int cg = w + 8 * i;
        float v0 = st0[i], v1 = st1[i];
        if (cg >= 4 && cg < 8) {
            v0 = fminf(v0, __shfl_xor(v0, 16));
            v0 = fminf(v0, __shfl_xor(v0, 32));
        } else if (cg >= 8 && cg < 12) {
            v0 = fmaxf(v0, __shfl_xor(v0, 16));
            v0 = fmaxf(v0, __shfl_xor(v0, 32));
        } else {
            v0 += __shfl_xor(v0, 16);
            v0 += __shfl_xor(v0, 32);
            if (cg >= 16) {
                v1 += __shfl_xor(v1, 16);
                v1 += __shfl_xor(v1, 32);
            }
        }
        if (lane < 16) {
            float* zg = z + (size_t)g * 384;
            int c = (cg & 3) * 16 + lane;
            if (cg < 16) zg[(cg >> 2) * 64 + c] = v0;
            else { zg[256 + c] = v0; zg[320 + c] = v1; }
        }
    }
}

// ---- K2: finalize z (mean, std) + GEMM2 (fp32) + bias -----------------------
__global__ __launch_bounds__(256) void k2_kernel(
    const float* __restrict__ z, const int* __restrict__ seg,
    const float* __restrict__ W2, const float* __restrict__ bias,
    float* __restrict__ out) {
    __shared__ float zf[320][16];  // transposed [k][m], 20 KB
    const int g0 = blockIdx.x * 16;
    const int tid = threadIdx.x;
    for (int idx = tid; idx < 16 * 320; idx += 256) {
        int c = idx >> 4;      // channel 0..319
        int m = idx & 15;      // graph within tile
        int g = g0 + m;
        float cnt = (float)max(1, seg[g + 1] - seg[g]);
        const float* zg = z + (size_t)g * 384;
        int a = c >> 6, cc = c & 63;
        float val;
        if (a == 0) val = zg[cc];
        else if (a == 1) val = zg[64 + cc];
        else if (a == 2) val = zg[128 + cc];
        else if (a == 3) val = zg[192 + cc] / cnt;
        else {
            float m1 = zg[256 + cc] / cnt;
            float m2 = zg[320 + cc] / cnt;
            val = sqrtf(fmaxf(m2 - m1 * m1, 1e-5f));
        }
        zf[c][m] = val;
    }
    __syncthreads();
    float acc[16];
#pragma unroll
    for (int m = 0; m < 16; ++m) acc[m] = 0.f;
    for (int k = 0; k < 320; ++k) {
        float wv = W2[(size_t)k * 256 + tid];
#pragma unroll
        for (int m = 0; m < 16; ++m) acc[m] += zf[k][m] * wv;
    }
    float bv = bias[tid];
#pragma unroll
    for (int m = 0; m < 16; ++m)
        out[(size_t)(g0 + m) * 256 + tid] = acc[m] + bv;
}

extern "C" void kernel_launch(void* const* d_in, const int* in_sizes, int n_in,
                              void* d_out, int out_size, void* d_ws, size_t ws_size,
                              hipStream_t stream) {
    const float* x = (const float*)d_in[0];
    const int* batch = (const int*)d_in[1];
    const float* W1 = (const float*)d_in[3];
    const float* W2 = (const float*)d_in[4];
    const float* bias = (const float*)d_in[5];

    const int n = in_sizes[1];           // 500000 nodes
    const int b_gr = out_size / 256;     // 8192 graphs

    char* ws = (char*)d_ws;
    unsigned short* w1p = (unsigned short*)ws;          // 163840 B (bf16 W1 pack)
    int* seg = (int*)(ws + 163840);                     // (B+1)*4 B
    float* z = (float*)(ws + 196864);                   // B*384*4 B ~= 12.6 MB

    seg_start_kernel<<<(b_gr + 256) / 256, 256, 0, stream>>>(batch, seg, n, b_gr);
    pack_w1_kernel<<<(NCG * 8 * 64 + 255) / 256, 256, 0, stream>>>(W1, w1p);
    aggr_kernel<<<b_gr, 512, 0, stream>>>(x, seg, w1p, z);
    k2_kernel<<<b_gr / 16, 256, 0, stream>>>(z, seg, W2, bias, (float*)d_out);
}

// Round 3
// 352.629 us; speedup vs baseline: 4.6202x; 4.6202x over previous
//
#include <hip/hip_runtime.h>
#include <float.h>
#include <stdint.h>

typedef __attribute__((ext_vector_type(8))) short bf16x8;
typedef __attribute__((ext_vector_type(4))) float f32x4;

#define NCH 320      // A*K = 5*64 output channels of GEMM1
#define NCG 20       // 320 / 16 channel-groups
#define CHUNK 64     // rows of x staged per iteration

static __device__ __forceinline__ unsigned short f2bf(float f) {
    union { float f; unsigned int u; } v; v.f = f;
    unsigned int u = v.u;
    u += 0x7FFFu + ((u >> 16) & 1u);   // round-to-nearest-even
    return (unsigned short)(u >> 16);
}

// ---- K0a: seg_start[b] = lower_bound(batch, b), b in [0, B] -----------------
__global__ void seg_start_kernel(const int* __restrict__ batch,
                                 int* __restrict__ seg, int n, int b_gr) {
    int b = blockIdx.x * blockDim.x + threadIdx.x;
    if (b > b_gr) return;
    int lo = 0, hi = n;
    while (lo < hi) {
        int mid = (lo + hi) >> 1;
        if (batch[mid] < b) lo = mid + 1; else hi = mid;
    }
    seg[b] = lo;
}

// ---- K0b: pack W1 (f32 [256][320]) into bf16 B-fragment layout --------------
// frag (cg, ks): lane l, elem j  <-  W1[k = ks*32 + (l>>4)*8 + j][c = cg*16 + (l&15)]
__global__ void pack_w1_kernel(const float* __restrict__ W1,
                               unsigned short* __restrict__ w1p) {
    int idx = blockIdx.x * blockDim.x + threadIdx.x;  // (cg*8 + ks)*64 + lane
    if (idx >= NCG * 8 * 64) return;
    int lane = idx & 63;
    int ks = (idx >> 6) & 7;
    int cg = idx >> 9;
    int col = cg * 16 + (lane & 15);
    int kbase = ks * 32 + (lane >> 4) * 8;
    unsigned short* dst = w1p + (size_t)idx * 8;
#pragma unroll
    for (int j = 0; j < 8; ++j)
        dst[j] = f2bf(W1[(size_t)(kbase + j) * NCH + col]);
}

// ---- K1: per-graph fused GEMM1 (bf16 MFMA) + segment reductions -------------
// 512 thr = 8 waves, one graph per block.
// wave w: row-tiles {2*(w&1), 2*(w&1)+1}, channel-groups [5*(w>>1), 5*(w>>1)+5)
// All fragments/accumulators are NAMED variables -> guaranteed VGPR (no scratch).
__global__ __launch_bounds__(512)
__attribute__((amdgpu_waves_per_eu(4, 4)))
void aggr_kernel(const float* __restrict__ x, const int* __restrict__ seg,
                 const unsigned short* __restrict__ w1p, float* __restrict__ z) {
    __shared__ unsigned short xs[CHUNK * 256];   // 32 KB, XOR-swizzled bf16
    __shared__ float red[4][5][16][2];           // cross-wave-pair reduce, 2.5 KB

    const int g = blockIdx.x;
    const int s = seg[g], e = seg[g + 1];
    const int tid = threadIdx.x;
    const int lane = tid & 63;
    const int w = tid >> 6;
    const int tp = w & 1;          // which pair of row-tiles
    const int cgrp = w >> 1;       // channel-group group
    const int cgbase = cgrp * 5;
    const int rg = lane >> 4;      // row-group within 16-row tile
    const int col = lane & 15;

    // 10 accumulators: c<rowtile><j>
    f32x4 c00 = {0,0,0,0}, c01 = {0,0,0,0}, c02 = {0,0,0,0}, c03 = {0,0,0,0}, c04 = {0,0,0,0};
    f32x4 c10 = {0,0,0,0}, c11 = {0,0,0,0}, c12 = {0,0,0,0}, c13 = {0,0,0,0}, c14 = {0,0,0,0};

    float st0[5], st1[5];
#pragma unroll
    for (int j = 0; j < 5; ++j) {
        int cg = cgbase + j;
        st0[j] = (cg >= 4 && cg < 8) ? FLT_MAX :
                 (cg >= 8 && cg < 12) ? -FLT_MAX : 0.f;
        st1[j] = 0.f;
    }

    const bf16x8* wp = (const bf16x8*)w1p;
    const int rowA0 = tp * 32 + col;       // A row for tile 2tp
    const int rowA1 = rowA0 + 16;          // A row for tile 2tp+1
    const int swz = (rowA0 & 7) << 4;      // same for rowA1 (row+16 keeps &7)
    const int a0base = rowA0 * 512 + rg * 16;
    const int a1base = rowA1 * 512 + rg * 16;
    const int r0 = tp * 32 + rg * 4;       // D-row base, tile 2tp
    const int r1 = r0 + 16;                // D-row base, tile 2tp+1

    for (int c0 = s; c0 < e; c0 += CHUNK) {
        const int rem = min(e - c0, CHUNK);
        __syncthreads();                   // previous chunk's LDS reads done
        // ---- stage chunk: f32 -> bf16, zero-pad to 64 rows, XOR swizzle ----
        {
            const float4* xv = (const float4*)x + (size_t)c0 * 64;
#pragma unroll
            for (int i = 0; i < 8; ++i) {
                int row = (tid >> 6) + i * 8;   // wave-uniform row
                float4 v = make_float4(0.f, 0.f, 0.f, 0.f);
                if (row < rem) v = xv[(size_t)row * 64 + lane];
                ushort4 h;
                h.x = f2bf(v.x); h.y = f2bf(v.y);
                h.z = f2bf(v.z); h.w = f2bf(v.w);
                int byt = (row * 512 + lane * 8) ^ ((row & 7) << 4);
                *(ushort4*)((char*)xs + byt) = h;
            }
        }
        __syncthreads();
        // ---- K loop: 8 steps of K=32; 7 frag loads -> 10 MFMAs per step ----
#pragma unroll 2
        for (int ks = 0; ks < 8; ++ks) {
            bf16x8 a0 = *(const bf16x8*)((const char*)xs + ((a0base + ks * 64) ^ swz));
            bf16x8 a1 = *(const bf16x8*)((const char*)xs + ((a1base + ks * 64) ^ swz));
            bf16x8 b0 = wp[((cgbase + 0) * 8 + ks) * 64 + lane];
            bf16x8 b1 = wp[((cgbase + 1) * 8 + ks) * 64 + lane];
            bf16x8 b2 = wp[((cgbase + 2) * 8 + ks) * 64 + lane];
            bf16x8 b3 = wp[((cgbase + 3) * 8 + ks) * 64 + lane];
            bf16x8 b4 = wp[((cgbase + 4) * 8 + ks) * 64 + lane];
            c00 = __builtin_amdgcn_mfma_f32_16x16x32_bf16(a0, b0, c00, 0, 0, 0);
            c10 = __builtin_amdgcn_mfma_f32_16x16x32_bf16(a1, b0, c10, 0, 0, 0);
            c01 = __builtin_amdgcn_mfma_f32_16x16x32_bf16(a0, b1, c01, 0, 0, 0);
            c11 = __builtin_amdgcn_mfma_f32_16x16x32_bf16(a1, b1, c11, 0, 0, 0);
            c02 = __builtin_amdgcn_mfma_f32_16x16x32_bf16(a0, b2, c02, 0, 0, 0);
            c12 = __builtin_amdgcn_mfma_f32_16x16x32_bf16(a1, b2, c12, 0, 0, 0);
            c03 = __builtin_amdgcn_mfma_f32_16x16x32_bf16(a0, b3, c03, 0, 0, 0);
            c13 = __builtin_amdgcn_mfma_f32_16x16x32_bf16(a1, b3, c13, 0, 0, 0);
            c04 = __builtin_amdgcn_mfma_f32_16x16x32_bf16(a0, b4, c04, 0, 0, 0);
            c14 = __builtin_amdgcn_mfma_f32_16x16x32_bf16(a1, b4, c14, 0, 0, 0);
        }
        // ---- fold accumulators into running stats, reset accs ----
        // D layout: row = tile*16 + rg*4 + r, col = lane&15
#define FOLD(j, C0, C1)                                                        \
        {                                                                      \
            int cg = cgbase + j;                                               \
            if (cg < 4 || (cg >= 12 && cg < 16)) {                             \
                st0[j] += C0[0] + C0[1] + C0[2] + C0[3]                        \
                        + C1[0] + C1[1] + C1[2] + C1[3];                       \
            } else if (cg < 8) {                                               \
                if (r0 + 0 < rem) st0[j] = fminf(st0[j], C0[0]);               \
                if (r0 + 1 < rem) st0[j] = fminf(st0[j], C0[1]);               \
                if (r0 + 2 < rem) st0[j] = fminf(st0[j], C0[2]);               \
                if (r0 + 3 < rem) st0[j] = fminf(st0[j], C0[3]);               \
                if (r1 + 0 < rem) st0[j] = fminf(st0[j], C1[0]);               \
                if (r1 + 1 < rem) st0[j] = fminf(st0[j], C1[1]);               \
                if (r1 + 2 < rem) st0[j] = fminf(st0[j], C1[2]);               \
                if (r1 + 3 < rem) st0[j] = fminf(st0[j], C1[3]);               \
            } else if (cg < 12) {                                              \
                if (r0 + 0 < rem) st0[j] = fmaxf(st0[j], C0[0]);               \
                if (r0 + 1 < rem) st0[j] = fmaxf(st0[j], C0[1]);               \
                if (r0 + 2 < rem) st0[j] = fmaxf(st0[j], C0[2]);               \
                if (r0 + 3 < rem) st0[j] = fmaxf(st0[j], C0[3]);               \
                if (r1 + 0 < rem) st0[j] = fmaxf(st0[j], C1[0]);               \
                if (r1 + 1 < rem) st0[j] = fmaxf(st0[j], C1[1]);               \
                if (r1 + 2 < rem) st0[j] = fmaxf(st0[j], C1[2]);               \
                if (r1 + 3 < rem) st0[j] = fmaxf(st0[j], C1[3]);               \
            } else {                                                           \
                st0[j] += C0[0] + C0[1] + C0[2] + C0[3]                        \
                        + C1[0] + C1[1] + C1[2] + C1[3];                       \
                st1[j] += C0[0]*C0[0] + C0[1]*C0[1] + C0[2]*C0[2] + C0[3]*C0[3]\
                        + C1[0]*C1[0] + C1[1]*C1[1] + C1[2]*C1[2] + C1[3]*C1[3];\
            }                                                                  \
            C0 = (f32x4){0.f,0.f,0.f,0.f}; C1 = (f32x4){0.f,0.f,0.f,0.f};      \
        }
        FOLD(0, c00, c10)
        FOLD(1, c01, c11)
        FOLD(2, c02, c12)
        FOLD(3, c03, c13)
        FOLD(4, c04, c14)
#undef FOLD
    }

    // ---- cross-lane reduce over row-groups (lane^16, lane^32) --------------
#pragma unroll
    for (int j = 0; j < 5; ++j) {
        int cg = cgbase + j;
        float v0 = st0[j], v1 = st1[j];
        if (cg >= 4 && cg < 8) {
            v0 = fminf(v0, __shfl_xor(v0, 16));
            v0 = fminf(v0, __shfl_xor(v0, 32));
        } else if (cg >= 8 && cg < 12) {
            v0 = fmaxf(v0, __shfl_xor(v0, 16));
            v0 = fmaxf(v0, __shfl_xor(v0, 32));
        } else {
            v0 += __shfl_xor(v0, 16);
            v0 += __shfl_xor(v0, 32);
            if (cg >= 16) { v1 += __shfl_xor(v1, 16); v1 += __shfl_xor(v1, 32); }
        }
        st0[j] = v0; st1[j] = v1;
    }
    // ---- combine the two row-tile waves of each cg-group, write z ----------
    if (tp == 1 && lane < 16) {
#pragma unroll
        for (int j = 0; j < 5; ++j) {
            red[cgrp][j][lane][0] = st0[j];
            red[cgrp][j][lane][1] = st1[j];
        }
    }
    __syncthreads();
    if (tp == 0 && lane < 16) {
        float* zg = z + (size_t)g * 384;
#pragma unroll
        for (int j = 0; j < 5; ++j) {
            int cg = cgbase + j;
            float p0 = red[cgrp][j][lane][0];
            float p1 = red[cgrp][j][lane][1];
            float v0 = st0[j], v1 = st1[j];
            if (cg >= 4 && cg < 8) v0 = fminf(v0, p0);
            else if (cg >= 8 && cg < 12) v0 = fmaxf(v0, p0);
            else { v0 += p0; v1 += p1; }
            if (cg < 16) zg[(cg >> 2) * 64 + (cg & 3) * 16 + lane] = v0;
            else {
                zg[256 + (cg - 16) * 16 + lane] = v0;
                zg[320 + (cg - 16) * 16 + lane] = v1;
            }
        }
    }
}

// ---- K2: finalize z (mean, std) + GEMM2 (fp32) + bias -----------------------
__global__ __launch_bounds__(256) void k2_kernel(
    const float* __restrict__ z, const int* __restrict__ seg,
    const float* __restrict__ W2, const float* __restrict__ bias,
    float* __restrict__ out) {
    __shared__ float zf[320][16];  // transposed [k][m], 20 KB
    const int g0 = blockIdx.x * 16;
    const int tid = threadIdx.x;
    for (int idx = tid; idx < 16 * 320; idx += 256) {
        int c = idx >> 4;      // channel 0..319
        int m = idx & 15;      // graph within tile
        int g = g0 + m;
        float cnt = (float)max(1, seg[g + 1] - seg[g]);
        const float* zg = z + (size_t)g * 384;
        int a = c >> 6, cc = c & 63;
        float val;
        if (a == 0) val = zg[cc];
        else if (a == 1) val = zg[64 + cc];
        else if (a == 2) val = zg[128 + cc];
        else if (a == 3) val = zg[192 + cc] / cnt;
        else {
            float m1 = zg[256 + cc] / cnt;
            float m2 = zg[320 + cc] / cnt;
            val = sqrtf(fmaxf(m2 - m1 * m1, 1e-5f));
        }
        zf[c][m] = val;
    }
    __syncthreads();
    float acc[16];
#pragma unroll
    for (int m = 0; m < 16; ++m) acc[m] = 0.f;
    for (int k = 0; k < 320; ++k) {
        float wv = W2[(size_t)k * 256 + tid];
#pragma unroll
        for (int m = 0; m < 16; ++m) acc[m] += zf[k][m] * wv;
    }
    float bv = bias[tid];
#pragma unroll
    for (int m = 0; m < 16; ++m)
        out[(size_t)(g0 + m) * 256 + tid] = acc[m] + bv;
}

extern "C" void kernel_launch(void* const* d_in, const int* in_sizes, int n_in,
                              void* d_out, int out_size, void* d_ws, size_t ws_size,
                              hipStream_t stream) {
    const float* x = (const float*)d_in[0];
    const int* batch = (const int*)d_in[1];
    const float* W1 = (const float*)d_in[3];
    const float* W2 = (const float*)d_in[4];
    const float* bias = (const float*)d_in[5];

    const int n = in_sizes[1];           // 500000 nodes
    const int b_gr = out_size / 256;     // 8192 graphs

    char* ws = (char*)d_ws;
    unsigned short* w1p = (unsigned short*)ws;          // 163840 B (bf16 W1 pack)
    int* seg = (int*)(ws + 163840);                     // (B+1)*4 B
    float* z = (float*)(ws + 196864);                   // B*384*4 B ~= 12.6 MB

    seg_start_kernel<<<(b_gr + 256) / 256, 256, 0, stream>>>(batch, seg, n, b_gr);
    pack_w1_kernel<<<(NCG * 8 * 64 + 255) / 256, 256, 0, stream>>>(W1, w1p);
    aggr_kernel<<<b_gr, 512, 0, stream>>>(x, seg, w1p, z);
    k2_kernel<<<b_gr / 16, 256, 0, stream>>>(z, seg, W2, bias, (float*)d_out);
}

// Round 4
// 333.043 us; speedup vs baseline: 4.8919x; 1.0588x over previous
//
#include <hip/hip_runtime.h>
#include <hip/hip_bf16.h>
#include <float.h>
#include <stdint.h>

typedef __attribute__((ext_vector_type(8))) short bf16x8;
typedef __attribute__((ext_vector_type(4))) float f32x4;

#define NCH 320      // A*K = 5*64 output channels of GEMM1
#define NCG 20       // 320 / 16 channel-groups
#define CHUNK 64     // rows of x staged per chunk
#define GPG 8        // graphs per block
#define NTHR 640     // 10 waves

static __device__ __forceinline__ unsigned short f2bf(float f) {
    union { float f; unsigned int u; } v; v.f = f;
    unsigned int u = v.u;
    u += 0x7FFFu + ((u >> 16) & 1u);   // RNE
    return (unsigned short)(u >> 16);
}

// ---- K0a: seg_start[b] = lower_bound(batch, b) ------------------------------
__global__ void seg_start_kernel(const int* __restrict__ batch,
                                 int* __restrict__ seg, int n, int b_gr) {
    int b = blockIdx.x * blockDim.x + threadIdx.x;
    if (b > b_gr) return;
    int lo = 0, hi = n;
    while (lo < hi) {
        int mid = (lo + hi) >> 1;
        if (batch[mid] < b) lo = mid + 1; else hi = mid;
    }
    seg[b] = lo;
}

// ---- K0b: pack W1 into bf16 B-fragment layout -------------------------------
// frag (cg, ks): lane l, elem j <- W1[k = ks*32 + (l>>4)*8 + j][c = cg*16 + (l&15)]
__global__ void pack_w1_kernel(const float* __restrict__ W1,
                               unsigned short* __restrict__ w1p) {
    int idx = blockIdx.x * blockDim.x + threadIdx.x;
    if (idx >= NCG * 8 * 64) return;
    int lane = idx & 63;
    int ks = (idx >> 6) & 7;
    int cg = idx >> 9;
    int col = cg * 16 + (lane & 15);
    int kbase = ks * 32 + (lane >> 4) * 8;
    unsigned short* dst = w1p + (size_t)idx * 8;
#pragma unroll
    for (int j = 0; j < 8; ++j)
        dst[j] = f2bf(W1[(size_t)(kbase + j) * NCH + col]);
}

// ---- K1: fused GEMM1 + segment reductions, 8 graphs/block -------------------
// 10 waves; wave w owns cgs {2w,2w+1} (one aggregator type/wave), all 4 tiles.
// B fragments persistent in registers (64 VGPR), A double-buffered in LDS.
__global__ __launch_bounds__(NTHR)
__attribute__((amdgpu_waves_per_eu(2)))
void aggr_kernel(const float* __restrict__ x, const int* __restrict__ seg,
                 const unsigned short* __restrict__ w1p, float* __restrict__ z) {
    __shared__ unsigned short xs[2][CHUNK * 256];   // 2 x 32 KB, XOR-swizzled

    const int g0 = blockIdx.x * GPG;
    const int tid = threadIdx.x;
    const int lane = tid & 63;
    const int w = tid >> 6;          // 0..9
    const int wtype = w >> 1;        // 0 sum, 1 min, 2 max, 3 mean, 4 std
    const int cg0 = 2 * w;
    const int rg = lane >> 4;
    const int col = lane & 15;

    // ---- persistent B fragments (loaded once) ----
    const bf16x8* wp = (const bf16x8*)w1p;
    bf16x8 Bf0[8], Bf1[8];
#pragma unroll
    for (int ks = 0; ks < 8; ++ks) {
        Bf0[ks] = wp[(cg0 * 8 + ks) * 64 + lane];
        Bf1[ks] = wp[((cg0 + 1) * 8 + ks) * 64 + lane];
    }

    // ---- per-ks swizzled LDS read offsets (t16*8192 added as immediate) ----
    int addrk[8];
#pragma unroll
    for (int ks = 0; ks < 8; ++ks)
        addrk[ks] = ((col * 512) + (rg * 16) + ks * 64) ^ ((col & 7) << 4);

    // ---- running stats ----
    const float id0 = (wtype == 1) ? FLT_MAX : (wtype == 2) ? -FLT_MAX : 0.f;
    float s0a = id0, s0b = id0, s1a = 0.f, s1b = 0.f;

    // ---- chunk iterators (all uniform / scalar) ----
    int sgi = 0, sch = 0, sS = seg[g0], sE = seg[g0 + 1];
    int snch = max(1, (sE - sS + CHUNK - 1) >> 6);
    int cgi = 0, cch = 0, cS = sS, cE = sE, cnch = snch;
    int TC = 0;
    {
        int ps = sS;
        for (int i = 0; i < GPG; ++i) {
            int pe = seg[g0 + i + 1];
            TC += max(1, (pe - ps + CHUNK - 1) >> 6);
            ps = pe;
        }
    }
    const float4* xv = (const float4*)x;

#define ADV_S { if (++sch == snch) { sgi++; sch = 0; if (sgi < GPG) { \
            sS = seg[g0 + sgi]; sE = seg[g0 + sgi + 1]; \
            snch = max(1, (sE - sS + CHUNK - 1) >> 6); } } }

#define LD1(i, dst) { int q = tid + (i) * NTHR; int row = q >> 6; \
        dst = make_float4(0.f, 0.f, 0.f, 0.f); \
        if (((i) < 6 || q < 4096) && row < rem_) \
            dst = xv[(size_t)(base_ + row) * 64 + (q & 63)]; }

#define ST1(i, src, xb) { int q = tid + (i) * NTHR; \
        if ((i) < 6 || q < 4096) { int row = q >> 6; \
            int byt = ((row * 512) + ((q & 63) * 8)) ^ ((row & 7) << 4); \
            __hip_bfloat162 lo2 = __float22bfloat162_rn(make_float2(src.x, src.y)); \
            __hip_bfloat162 hi2 = __float22bfloat162_rn(make_float2(src.z, src.w)); \
            unsigned int ulo, uhi; \
            __builtin_memcpy(&ulo, &lo2, 4); __builtin_memcpy(&uhi, &hi2, 4); \
            *(uint2*)((char*)(xb) + byt) = make_uint2(ulo, uhi); } }

    // ---- prologue: stage chunk 0 into buf 0 ----
    {
        const int base_ = sS;
        const int rem_ = min(sE - base_, CHUNK);
        float4 p0, p1, p2, p3, p4, p5, p6;
        LD1(0, p0) LD1(1, p1) LD1(2, p2) LD1(3, p3) LD1(4, p4) LD1(5, p5) LD1(6, p6)
        ST1(0, p0, xs[0]) ST1(1, p1, xs[0]) ST1(2, p2, xs[0]) ST1(3, p3, xs[0])
        ST1(4, p4, xs[0]) ST1(5, p5, xs[0]) ST1(6, p6, xs[0])
    }
    ADV_S
    __syncthreads();

    int cur = 0;
    for (int t = 0; t < TC; ++t) {
        const bool more = (t + 1 < TC);
        // ---- issue next chunk's global loads (latency hides under MFMA) ----
        float4 p0, p1, p2, p3, p4, p5, p6;
        if (more) {
            const int base_ = sS + (sch << 6);
            const int rem_ = min(sE - base_, CHUNK);
            LD1(0, p0) LD1(1, p1) LD1(2, p2) LD1(3, p3) LD1(4, p4) LD1(5, p5) LD1(6, p6)
        }
        // ---- compute current chunk from xs[cur] ----
        const int crem = min(cE - (cS + (cch << 6)), CHUNK);
        f32x4 a00 = {0,0,0,0}, a01 = {0,0,0,0}, a10 = {0,0,0,0}, a11 = {0,0,0,0};
        f32x4 a20 = {0,0,0,0}, a21 = {0,0,0,0}, a30 = {0,0,0,0}, a31 = {0,0,0,0};
        {
            const char* pb = (const char*)xs[cur];
#pragma unroll
            for (int ks = 0; ks < 8; ++ks) {
                bf16x8 x0 = *(const bf16x8*)(pb + addrk[ks]);
                bf16x8 x1 = *(const bf16x8*)(pb + addrk[ks] + 8192);
                bf16x8 x2 = *(const bf16x8*)(pb + addrk[ks] + 16384);
                bf16x8 x3 = *(const bf16x8*)(pb + addrk[ks] + 24576);
                a00 = __builtin_amdgcn_mfma_f32_16x16x32_bf16(x0, Bf0[ks], a00, 0, 0, 0);
                a01 = __builtin_amdgcn_mfma_f32_16x16x32_bf16(x0, Bf1[ks], a01, 0, 0, 0);
                a10 = __builtin_amdgcn_mfma_f32_16x16x32_bf16(x1, Bf0[ks], a10, 0, 0, 0);
                a11 = __builtin_amdgcn_mfma_f32_16x16x32_bf16(x1, Bf1[ks], a11, 0, 0, 0);
                a20 = __builtin_amdgcn_mfma_f32_16x16x32_bf16(x2, Bf0[ks], a20, 0, 0, 0);
                a21 = __builtin_amdgcn_mfma_f32_16x16x32_bf16(x2, Bf1[ks], a21, 0, 0, 0);
                a30 = __builtin_amdgcn_mfma_f32_16x16x32_bf16(x3, Bf0[ks], a30, 0, 0, 0);
                a31 = __builtin_amdgcn_mfma_f32_16x16x32_bf16(x3, Bf1[ks], a31, 0, 0, 0);
            }
        }
        // ---- fold into running stats (wave-uniform aggregator type) ----
#define SUM4(v) ((v)[0] + (v)[1] + (v)[2] + (v)[3])
        if (wtype == 1) {
#define MFOLD(t16, A, B) { int rb = (t16) * 16 + (rg << 2); \
            if (rb + 0 < crem) { s0a = fminf(s0a, (A)[0]); s0b = fminf(s0b, (B)[0]); } \
            if (rb + 1 < crem) { s0a = fminf(s0a, (A)[1]); s0b = fminf(s0b, (B)[1]); } \
            if (rb + 2 < crem) { s0a = fminf(s0a, (A)[2]); s0b = fminf(s0b, (B)[2]); } \
            if (rb + 3 < crem) { s0a = fminf(s0a, (A)[3]); s0b = fminf(s0b, (B)[3]); } }
            MFOLD(0, a00, a01) MFOLD(1, a10, a11) MFOLD(2, a20, a21) MFOLD(3, a30, a31)
#undef MFOLD
        } else if (wtype == 2) {
#define MFOLD(t16, A, B) { int rb = (t16) * 16 + (rg << 2); \
            if (rb + 0 < crem) { s0a = fmaxf(s0a, (A)[0]); s0b = fmaxf(s0b, (B)[0]); } \
            if (rb + 1 < crem) { s0a = fmaxf(s0a, (A)[1]); s0b = fmaxf(s0b, (B)[1]); } \
            if (rb + 2 < crem) { s0a = fmaxf(s0a, (A)[2]); s0b = fmaxf(s0b, (B)[2]); } \
            if (rb + 3 < crem) { s0a = fmaxf(s0a, (A)[3]); s0b = fmaxf(s0b, (B)[3]); } }
            MFOLD(0, a00, a01) MFOLD(1, a10, a11) MFOLD(2, a20, a21) MFOLD(3, a30, a31)
#undef MFOLD
        } else if (wtype == 4) {
            s0a += SUM4(a00) + SUM4(a10) + SUM4(a20) + SUM4(a30);
            s0b += SUM4(a01) + SUM4(a11) + SUM4(a21) + SUM4(a31);
            s1a += a00[0]*a00[0] + a00[1]*a00[1] + a00[2]*a00[2] + a00[3]*a00[3]
                 + a10[0]*a10[0] + a10[1]*a10[1] + a10[2]*a10[2] + a10[3]*a10[3]
                 + a20[0]*a20[0] + a20[1]*a20[1] + a20[2]*a20[2] + a20[3]*a20[3]
                 + a30[0]*a30[0] + a30[1]*a30[1] + a30[2]*a30[2] + a30[3]*a30[3];
            s1b += a01[0]*a01[0] + a01[1]*a01[1] + a01[2]*a01[2] + a01[3]*a01[3]
                 + a11[0]*a11[0] + a11[1]*a11[1] + a11[2]*a11[2] + a11[3]*a11[3]
                 + a21[0]*a21[0] + a21[1]*a21[1] + a21[2]*a21[2] + a21[3]*a21[3]
                 + a31[0]*a31[0] + a31[1]*a31[1] + a31[2]*a31[2] + a31[3]*a31[3];
        } else {
            s0a += SUM4(a00) + SUM4(a10) + SUM4(a20) + SUM4(a30);
            s0b += SUM4(a01) + SUM4(a11) + SUM4(a21) + SUM4(a31);
        }
#undef SUM4
        // ---- graph end: cross-lane reduce over row-groups, write z ----
        if (cch == cnch - 1) {
            float v0a = s0a, v0b = s0b, v1a = s1a, v1b = s1b;
            if (wtype == 1) {
                v0a = fminf(v0a, __shfl_xor(v0a, 16)); v0a = fminf(v0a, __shfl_xor(v0a, 32));
                v0b = fminf(v0b, __shfl_xor(v0b, 16)); v0b = fminf(v0b, __shfl_xor(v0b, 32));
            } else if (wtype == 2) {
                v0a = fmaxf(v0a, __shfl_xor(v0a, 16)); v0a = fmaxf(v0a, __shfl_xor(v0a, 32));
                v0b = fmaxf(v0b, __shfl_xor(v0b, 16)); v0b = fmaxf(v0b, __shfl_xor(v0b, 32));
            } else {
                v0a += __shfl_xor(v0a, 16); v0a += __shfl_xor(v0a, 32);
                v0b += __shfl_xor(v0b, 16); v0b += __shfl_xor(v0b, 32);
                if (wtype == 4) {
                    v1a += __shfl_xor(v1a, 16); v1a += __shfl_xor(v1a, 32);
                    v1b += __shfl_xor(v1b, 16); v1b += __shfl_xor(v1b, 32);
                }
            }
            if (lane < 16) {
                float* zg = z + (size_t)(g0 + cgi) * 384;
                if (wtype < 4) {
                    zg[wtype * 64 + (cg0 & 3) * 16 + lane] = v0a;
                    zg[wtype * 64 + ((cg0 + 1) & 3) * 16 + lane] = v0b;
                } else {
                    zg[256 + (cg0 - 16) * 16 + lane] = v0a;
                    zg[256 + (cg0 - 15) * 16 + lane] = v0b;
                    zg[320 + (cg0 - 16) * 16 + lane] = v1a;
                    zg[320 + (cg0 - 15) * 16 + lane] = v1b;
                }
            }
            s0a = id0; s0b = id0; s1a = 0.f; s1b = 0.f;
        }
        // advance compute iterator
        if (++cch == cnch) {
            cgi++; cch = 0;
            if (cgi < GPG) {
                cS = seg[g0 + cgi]; cE = seg[g0 + cgi + 1];
                cnch = max(1, (cE - cS + CHUNK - 1) >> 6);
            }
        }
        // ---- drain loads, convert, write next buffer, barrier ----
        if (more) {
            unsigned short* xb = xs[cur ^ 1];
            ST1(0, p0, xb) ST1(1, p1, xb) ST1(2, p2, xb) ST1(3, p3, xb)
            ST1(4, p4, xb) ST1(5, p5, xb) ST1(6, p6, xb)
            ADV_S
            __syncthreads();
        }
        cur ^= 1;
    }
#undef ADV_S
#undef LD1
#undef ST1
}

// ---- K2: finalize z (mean, std) + GEMM2 (fp32) + bias -----------------------
__global__ __launch_bounds__(256) void k2_kernel(
    const float* __restrict__ z, const int* __restrict__ seg,
    const float* __restrict__ W2, const float* __restrict__ bias,
    float* __restrict__ out) {
    __shared__ float zf[320][16];
    const int g0 = blockIdx.x * 16;
    const int tid = threadIdx.x;
    for (int idx = tid; idx < 16 * 320; idx += 256) {
        int c = idx >> 4;
        int m = idx & 15;
        int g = g0 + m;
        float cnt = (float)max(1, seg[g + 1] - seg[g]);
        const float* zg = z + (size_t)g * 384;
        int a = c >> 6, cc = c & 63;
        float val;
        if (a == 0) val = zg[cc];
        else if (a == 1) val = zg[64 + cc];
        else if (a == 2) val = zg[128 + cc];
        else if (a == 3) val = zg[192 + cc] / cnt;
        else {
            float m1 = zg[256 + cc] / cnt;
            float m2 = zg[320 + cc] / cnt;
            val = sqrtf(fmaxf(m2 - m1 * m1, 1e-5f));
        }
        zf[c][m] = val;
    }
    __syncthreads();
    float acc[16];
#pragma unroll
    for (int m = 0; m < 16; ++m) acc[m] = 0.f;
    for (int k = 0; k < 320; ++k) {
        float wv = W2[(size_t)k * 256 + tid];
#pragma unroll
        for (int m = 0; m < 16; ++m) acc[m] += zf[k][m] * wv;
    }
    float bv = bias[tid];
#pragma unroll
    for (int m = 0; m < 16; ++m)
        out[(size_t)(g0 + m) * 256 + tid] = acc[m] + bv;
}

extern "C" void kernel_launch(void* const* d_in, const int* in_sizes, int n_in,
                              void* d_out, int out_size, void* d_ws, size_t ws_size,
                              hipStream_t stream) {
    const float* x = (const float*)d_in[0];
    const int* batch = (const int*)d_in[1];
    const float* W1 = (const float*)d_in[3];
    const float* W2 = (const float*)d_in[4];
    const float* bias = (const float*)d_in[5];

    const int n = in_sizes[1];           // 500000 nodes
    const int b_gr = out_size / 256;     // 8192 graphs

    char* ws = (char*)d_ws;
    unsigned short* w1p = (unsigned short*)ws;          // 163840 B
    int* seg = (int*)(ws + 163840);                     // (B+1)*4
    float* z = (float*)(ws + 196864);                   // B*384*4 ~= 12.6 MB

    seg_start_kernel<<<(b_gr + 256) / 256, 256, 0, stream>>>(batch, seg, n, b_gr);
    pack_w1_kernel<<<(NCG * 8 * 64 + 255) / 256, 256, 0, stream>>>(W1, w1p);
    aggr_kernel<<<b_gr / GPG, NTHR, 0, stream>>>(x, seg, w1p, z);
    k2_kernel<<<b_gr / 16, 256, 0, stream>>>(z, seg, W2, bias, (float*)d_out);
}

// Round 5
// 330.553 us; speedup vs baseline: 4.9288x; 1.0075x over previous
//
#include <hip/hip_runtime.h>
#include <hip/hip_bf16.h>
#include <float.h>
#include <stdint.h>

typedef __attribute__((ext_vector_type(8))) short bf16x8;
typedef __attribute__((ext_vector_type(4))) float f32x4;

#define NCH 320      // A*K = 5*64 output channels of GEMM1
#define NCG 20       // 320 / 16 channel-groups
#define CHUNK 64     // rows of x staged per chunk
#define GPG 8        // graphs per block
#define NTHR 512     // 8 waves: ceil(8/4)=2 waves/SIMD -> 256-VGPR cap

static __device__ __forceinline__ unsigned short f2bf(float f) {
    union { float f; unsigned int u; } v; v.f = f;
    unsigned int u = v.u;
    u += 0x7FFFu + ((u >> 16) & 1u);   // RNE
    return (unsigned short)(u >> 16);
}

// ---- K0a: seg_start[b] = lower_bound(batch, b) ------------------------------
__global__ void seg_start_kernel(const int* __restrict__ batch,
                                 int* __restrict__ seg, int n, int b_gr) {
    int b = blockIdx.x * blockDim.x + threadIdx.x;
    if (b > b_gr) return;
    int lo = 0, hi = n;
    while (lo < hi) {
        int mid = (lo + hi) >> 1;
        if (batch[mid] < b) lo = mid + 1; else hi = mid;
    }
    seg[b] = lo;
}

// ---- K0b: pack W1 into bf16 B-fragment layout -------------------------------
// frag (cg, ks): lane l, elem j <- W1[k = ks*32 + (l>>4)*8 + j][c = cg*16 + (l&15)]
__global__ void pack_w1_kernel(const float* __restrict__ W1,
                               unsigned short* __restrict__ w1p) {
    int idx = blockIdx.x * blockDim.x + threadIdx.x;
    if (idx >= NCG * 8 * 64) return;
    int lane = idx & 63;
    int ks = (idx >> 6) & 7;
    int cg = idx >> 9;
    int col = cg * 16 + (lane & 15);
    int kbase = ks * 32 + (lane >> 4) * 8;
    unsigned short* dst = w1p + (size_t)idx * 8;
#pragma unroll
    for (int j = 0; j < 8; ++j)
        dst[j] = f2bf(W1[(size_t)(kbase + j) * NCH + col]);
}

// ---- K1: fused GEMM1 + segment reductions -----------------------------------
// 8 waves. Wave w: main cgs {2w, 2w+1} (type-uniform: w>>1 = sum/min/max/mean),
// plus std cg 16+(w&3) on row-tiles [2*(w>>2), 2*(w>>2)+1] (reuses A-frags).
// B fragments register-pinned. A triple-buffered in LDS (96 KB -> 1 block/CU).
__global__ __launch_bounds__(NTHR)
__attribute__((amdgpu_waves_per_eu(2)))
void aggr_kernel(const float* __restrict__ x, const int* __restrict__ seg,
                 const unsigned short* __restrict__ w1p, float* __restrict__ z) {
    __shared__ unsigned short xs[3 * CHUNK * 256];   // 3 x 32 KB, XOR-swizzled

    const int g0 = blockIdx.x * GPG;
    const int tid = threadIdx.x;
    const int lane = tid & 63;
    const int w = tid >> 6;            // 0..7
    const int cg0 = 2 * w;             // main cgs cg0, cg0+1 in [0,16)
    const int wtype = w >> 1;          // 0 sum, 1 min, 2 max, 3 mean
    const int sthalf = w >> 2;         // std rows: 0 -> tiles 0-1, 1 -> tiles 2-3
    const int rg = lane >> 4;
    const int col = lane & 15;

    // ---- persistent B fragments, pinned so they cannot be re-materialized ----
    const bf16x8* wp = (const bf16x8*)w1p;
    bf16x8 Bm0[8], Bm1[8], Bs[8];
#pragma unroll
    for (int ks = 0; ks < 8; ++ks) {
        Bm0[ks] = wp[(cg0 * 8 + ks) * 64 + lane];
        Bm1[ks] = wp[((cg0 + 1) * 8 + ks) * 64 + lane];
        Bs[ks]  = wp[((16 + (w & 3)) * 8 + ks) * 64 + lane];
        asm volatile("" : "+v"(Bm0[ks]));
        asm volatile("" : "+v"(Bm1[ks]));
        asm volatile("" : "+v"(Bs[ks]));
    }

    // ---- per-ks swizzled LDS read offsets ----
    int addrk[8];
#pragma unroll
    for (int ks = 0; ks < 8; ++ks)
        addrk[ks] = ((col * 512) + (rg * 16) + ks * 64) ^ ((col & 7) << 4);

    // ---- running stats ----
    const float id0 = (wtype == 1) ? FLT_MAX : (wtype == 2) ? -FLT_MAX : 0.f;
    float s0a = id0, s0b = id0;        // main cg0, cg0+1
    float ss0 = 0.f, ss1 = 0.f;        // std partial sum / sumsq

    // ---- chunk iterators (wave-uniform) ----
    int sgi = 0, sch = 0, sS = seg[g0], sE = seg[g0 + 1];
    int snch = max(1, (sE - sS + CHUNK - 1) >> 6);
    int cgi = 0, cch = 0, cS = sS, cE = sE, cnch = snch;
    int TC = 0;
    {
        int ps = sS;
        for (int i = 0; i < GPG; ++i) {
            int pe = seg[g0 + i + 1];
            TC += max(1, (pe - ps + CHUNK - 1) >> 6);
            ps = pe;
        }
    }
    const float4* xv = (const float4*)x;

#define ADV_S { if (++sch == snch) { sgi++; sch = 0; if (sgi < GPG) { \
            sS = seg[g0 + sgi]; sE = seg[g0 + sgi + 1]; \
            snch = max(1, (sE - sS + CHUNK - 1) >> 6); } } }

    // 512 thr x 8 iters = 4096 float4 = 64 rows x 64 float4: exact, no bounds chk
#define LD1(i, dst) { int q = tid + (i) * NTHR; int row = q >> 6; \
        dst = make_float4(0.f, 0.f, 0.f, 0.f); \
        if (row < rem_) dst = xv[(size_t)(base_ + row) * 64 + (q & 63)]; }

#define ST1(i, src, xb) { int q = tid + (i) * NTHR; int row = q >> 6; \
        int byt = ((row * 512) + ((q & 63) * 8)) ^ ((row & 7) << 4); \
        __hip_bfloat162 lo2 = __float22bfloat162_rn(make_float2(src.x, src.y)); \
        __hip_bfloat162 hi2 = __float22bfloat162_rn(make_float2(src.z, src.w)); \
        unsigned int ulo, uhi; \
        __builtin_memcpy(&ulo, &lo2, 4); __builtin_memcpy(&uhi, &hi2, 4); \
        *(uint2*)((xb) + byt) = make_uint2(ulo, uhi); }

    // ---- prologue: stage chunk 0 into buffer 0 ----
    {
        const int base_ = sS;
        const int rem_ = min(sE - base_, CHUNK);
        float4 p0, p1, p2, p3, p4, p5, p6, p7;
        LD1(0, p0) LD1(1, p1) LD1(2, p2) LD1(3, p3)
        LD1(4, p4) LD1(5, p5) LD1(6, p6) LD1(7, p7)
        char* xb = (char*)xs;
        ST1(0, p0, xb) ST1(1, p1, xb) ST1(2, p2, xb) ST1(3, p3, xb)
        ST1(4, p4, xb) ST1(5, p5, xb) ST1(6, p6, xb) ST1(7, p7, xb)
    }
    ADV_S
    __syncthreads();

    int bc = 0, bwi = 1;               // compute buffer / write buffer (0..2)
    for (int t = 0; t < TC; ++t) {
        const bool more = (t + 1 < TC);
        // ---- issue next chunk's global loads (hidden under compute) ----
        float4 p0, p1, p2, p3, p4, p5, p6, p7;
        if (more) {
            const int base_ = sS + (sch << 6);
            const int rem_ = min(sE - base_, CHUNK);
            LD1(0, p0) LD1(1, p1) LD1(2, p2) LD1(3, p3)
            LD1(4, p4) LD1(5, p5) LD1(6, p6) LD1(7, p7)
        }
        // ---- compute current chunk: pure LDS reads + MFMA ----
        const int crem = min(cE - (cS + (cch << 6)), CHUNK);
        f32x4 a00 = {0,0,0,0}, a01 = {0,0,0,0}, a10 = {0,0,0,0}, a11 = {0,0,0,0};
        f32x4 a20 = {0,0,0,0}, a21 = {0,0,0,0}, a30 = {0,0,0,0}, a31 = {0,0,0,0};
        f32x4 as0 = {0,0,0,0}, as1 = {0,0,0,0};
        {
            const char* pb = (const char*)xs + bc * 32768;
#pragma unroll
            for (int ks = 0; ks < 8; ++ks) {
                bf16x8 x0 = *(const bf16x8*)(pb + addrk[ks]);
                bf16x8 x1 = *(const bf16x8*)(pb + addrk[ks] + 8192);
                bf16x8 x2 = *(const bf16x8*)(pb + addrk[ks] + 16384);
                bf16x8 x3 = *(const bf16x8*)(pb + addrk[ks] + 24576);
                a00 = __builtin_amdgcn_mfma_f32_16x16x32_bf16(x0, Bm0[ks], a00, 0, 0, 0);
                a01 = __builtin_amdgcn_mfma_f32_16x16x32_bf16(x0, Bm1[ks], a01, 0, 0, 0);
                a10 = __builtin_amdgcn_mfma_f32_16x16x32_bf16(x1, Bm0[ks], a10, 0, 0, 0);
                a11 = __builtin_amdgcn_mfma_f32_16x16x32_bf16(x1, Bm1[ks], a11, 0, 0, 0);
                a20 = __builtin_amdgcn_mfma_f32_16x16x32_bf16(x2, Bm0[ks], a20, 0, 0, 0);
                a21 = __builtin_amdgcn_mfma_f32_16x16x32_bf16(x2, Bm1[ks], a21, 0, 0, 0);
                a30 = __builtin_amdgcn_mfma_f32_16x16x32_bf16(x3, Bm0[ks], a30, 0, 0, 0);
                a31 = __builtin_amdgcn_mfma_f32_16x16x32_bf16(x3, Bm1[ks], a31, 0, 0, 0);
                if (sthalf == 0) {     // wave-uniform branch
                    as0 = __builtin_amdgcn_mfma_f32_16x16x32_bf16(x0, Bs[ks], as0, 0, 0, 0);
                    as1 = __builtin_amdgcn_mfma_f32_16x16x32_bf16(x1, Bs[ks], as1, 0, 0, 0);
                } else {
                    as0 = __builtin_amdgcn_mfma_f32_16x16x32_bf16(x2, Bs[ks], as0, 0, 0, 0);
                    as1 = __builtin_amdgcn_mfma_f32_16x16x32_bf16(x3, Bs[ks], as1, 0, 0, 0);
                }
            }
        }
        // ---- fold into running stats (wave-uniform aggregator types) ----
#define SUM4(v) ((v)[0] + (v)[1] + (v)[2] + (v)[3])
        if (wtype == 1) {
#define MFOLD(t16, A, B) { int rb = (t16) * 16 + (rg << 2); \
            if (rb + 0 < crem) { s0a = fminf(s0a, (A)[0]); s0b = fminf(s0b, (B)[0]); } \
            if (rb + 1 < crem) { s0a = fminf(s0a, (A)[1]); s0b = fminf(s0b, (B)[1]); } \
            if (rb + 2 < crem) { s0a = fminf(s0a, (A)[2]); s0b = fminf(s0b, (B)[2]); } \
            if (rb + 3 < crem) { s0a = fminf(s0a, (A)[3]); s0b = fminf(s0b, (B)[3]); } }
            MFOLD(0, a00, a01) MFOLD(1, a10, a11) MFOLD(2, a20, a21) MFOLD(3, a30, a31)
#undef MFOLD
        } else if (wtype == 2) {
#define MFOLD(t16, A, B) { int rb = (t16) * 16 + (rg << 2); \
            if (rb + 0 < crem) { s0a = fmaxf(s0a, (A)[0]); s0b = fmaxf(s0b, (B)[0]); } \
            if (rb + 1 < crem) { s0a = fmaxf(s0a, (A)[1]); s0b = fmaxf(s0b, (B)[1]); } \
            if (rb + 2 < crem) { s0a = fmaxf(s0a, (A)[2]); s0b = fmaxf(s0b, (B)[2]); } \
            if (rb + 3 < crem) { s0a = fmaxf(s0a, (A)[3]); s0b = fmaxf(s0b, (B)[3]); } }
            MFOLD(0, a00, a01) MFOLD(1, a10, a11) MFOLD(2, a20, a21) MFOLD(3, a30, a31)
#undef MFOLD
        } else {
            s0a += SUM4(a00) + SUM4(a10) + SUM4(a20) + SUM4(a30);
            s0b += SUM4(a01) + SUM4(a11) + SUM4(a21) + SUM4(a31);
        }
        ss0 += SUM4(as0) + SUM4(as1);
        ss1 += as0[0]*as0[0] + as0[1]*as0[1] + as0[2]*as0[2] + as0[3]*as0[3]
             + as1[0]*as1[0] + as1[1]*as1[1] + as1[2]*as1[2] + as1[3]*as1[3];
#undef SUM4
        // ---- graph end: cross-lane reduce, write/atomic z ----
        if (cch == cnch - 1) {
            float v0a = s0a, v0b = s0b, w0 = ss0, w1 = ss1;
            if (wtype == 1) {
                v0a = fminf(v0a, __shfl_xor(v0a, 16)); v0a = fminf(v0a, __shfl_xor(v0a, 32));
                v0b = fminf(v0b, __shfl_xor(v0b, 16)); v0b = fminf(v0b, __shfl_xor(v0b, 32));
            } else if (wtype == 2) {
                v0a = fmaxf(v0a, __shfl_xor(v0a, 16)); v0a = fmaxf(v0a, __shfl_xor(v0a, 32));
                v0b = fmaxf(v0b, __shfl_xor(v0b, 16)); v0b = fmaxf(v0b, __shfl_xor(v0b, 32));
            } else {
                v0a += __shfl_xor(v0a, 16); v0a += __shfl_xor(v0a, 32);
                v0b += __shfl_xor(v0b, 16); v0b += __shfl_xor(v0b, 32);
            }
            w0 += __shfl_xor(w0, 16); w0 += __shfl_xor(w0, 32);
            w1 += __shfl_xor(w1, 16); w1 += __shfl_xor(w1, 32);
            if (lane < 16) {
                float* zg = z + (size_t)(g0 + cgi) * 384;
                zg[wtype * 64 + (cg0 & 3) * 16 + lane] = v0a;
                zg[wtype * 64 + ((cg0 & 3) + 1) * 16 + lane] = v0b;
                atomicAdd(&zg[256 + (w & 3) * 16 + lane], w0);
                atomicAdd(&zg[320 + (w & 3) * 16 + lane], w1);
            }
            s0a = id0; s0b = id0; ss0 = 0.f; ss1 = 0.f;
        }
        // advance compute iterator
        if (++cch == cnch) {
            cgi++; cch = 0;
            if (cgi < GPG) {
                cS = seg[g0 + cgi]; cE = seg[g0 + cgi + 1];
                cnch = max(1, (cE - cS + CHUNK - 1) >> 6);
            }
        }
        // ---- drain loads, convert, write next buffer, barrier ----
        if (more) {
            char* xb = (char*)xs + bwi * 32768;
            ST1(0, p0, xb) ST1(1, p1, xb) ST1(2, p2, xb) ST1(3, p3, xb)
            ST1(4, p4, xb) ST1(5, p5, xb) ST1(6, p6, xb) ST1(7, p7, xb)
            ADV_S
            __syncthreads();
        }
        bc = bwi;
        bwi = (bwi == 2) ? 0 : bwi + 1;
    }
#undef ADV_S
#undef LD1
#undef ST1
}

// ---- K2: finalize z (mean, std) + GEMM2 (fp32) + bias -----------------------
__global__ __launch_bounds__(256) void k2_kernel(
    const float* __restrict__ z, const int* __restrict__ seg,
    const float* __restrict__ W2, const float* __restrict__ bias,
    float* __restrict__ out) {
    __shared__ float zf[320][16];
    const int g0 = blockIdx.x * 16;
    const int tid = threadIdx.x;
    for (int idx = tid; idx < 16 * 320; idx += 256) {
        int c = idx >> 4;
        int m = idx & 15;
        int g = g0 + m;
        float cnt = (float)max(1, seg[g + 1] - seg[g]);
        const float* zg = z + (size_t)g * 384;
        int a = c >> 6, cc = c & 63;
        float val;
        if (a == 0) val = zg[cc];
        else if (a == 1) val = zg[64 + cc];
        else if (a == 2) val = zg[128 + cc];
        else if (a == 3) val = zg[192 + cc] / cnt;
        else {
            float m1 = zg[256 + cc] / cnt;
            float m2 = zg[320 + cc] / cnt;
            val = sqrtf(fmaxf(m2 - m1 * m1, 1e-5f));
        }
        zf[c][m] = val;
    }
    __syncthreads();
    float acc[16];
#pragma unroll
    for (int m = 0; m < 16; ++m) acc[m] = 0.f;
    for (int k = 0; k < 320; ++k) {
        float wv = W2[(size_t)k * 256 + tid];
#pragma unroll
        for (int m = 0; m < 16; ++m) acc[m] += zf[k][m] * wv;
    }
    float bv = bias[tid];
#pragma unroll
    for (int m = 0; m < 16; ++m)
        out[(size_t)(g0 + m) * 256 + tid] = acc[m] + bv;
}

extern "C" void kernel_launch(void* const* d_in, const int* in_sizes, int n_in,
                              void* d_out, int out_size, void* d_ws, size_t ws_size,
                              hipStream_t stream) {
    const float* x = (const float*)d_in[0];
    const int* batch = (const int*)d_in[1];
    const float* W1 = (const float*)d_in[3];
    const float* W2 = (const float*)d_in[4];
    const float* bias = (const float*)d_in[5];

    const int n = in_sizes[1];           // 500000 nodes
    const int b_gr = out_size / 256;     // 8192 graphs

    char* ws = (char*)d_ws;
    unsigned short* w1p = (unsigned short*)ws;          // 163840 B
    int* seg = (int*)(ws + 163840);                     // (B+1)*4
    float* z = (float*)(ws + 196864);                   // B*384*4 ~= 12.6 MB

    seg_start_kernel<<<(b_gr + 256) / 256, 256, 0, stream>>>(batch, seg, n, b_gr);
    pack_w1_kernel<<<(NCG * 8 * 64 + 255) / 256, 256, 0, stream>>>(W1, w1p);
    hipMemsetAsync(z, 0, (size_t)b_gr * 384 * sizeof(float), stream);  // std atomics base
    aggr_kernel<<<b_gr / GPG, NTHR, 0, stream>>>(x, seg, w1p, z);
    k2_kernel<<<b_gr / 16, 256, 0, stream>>>(z, seg, W2, bias, (float*)d_out);
}